// Round 1
// baseline (137.538 us; speedup 1.0000x reference)
//
#include <hip/hip_runtime.h>
#include <hip/hip_bf16.h>

typedef __attribute__((ext_vector_type(8))) __bf16 bf16x8;
typedef __attribute__((ext_vector_type(4))) float f32x4;

// ---------------------------------------------------------------------------
// Prep: W1 [128 (k=2D) rows][128 (H) cols] f32  ->  W1t [col][k] bf16 in ws.
// B-fragment for MFMA wants 8 contiguous k-elements at fixed col.
// ---------------------------------------------------------------------------
__global__ void prep_w1_kernel(const float* __restrict__ W1,
                               __bf16* __restrict__ W1t) {
    int i = blockIdx.x * 256 + threadIdx.x;   // i = c*128 + k, 16384 total
    int c = i >> 7;
    int k = i & 127;
    W1t[i] = (__bf16)W1[k * 128 + c];
}

// ---------------------------------------------------------------------------
// Main: one wave per 16-edge tile (= one dst node, DEG=16).
//   X[row][0:64]  = nf[dst]   (same for all rows of tile)
//   X[row][64:128]= nf[src[row]]
//   H = leaky(X @ W1 + b1); score = H @ W2 + b2  -> out[d*K + row]
//   slots DEG..K-1 = -1e10
// W1 (B operand) lives entirely in registers: 32 x bf16x8 = 128 VGPR.
// ---------------------------------------------------------------------------
__global__ __launch_bounds__(256, 2) void attack_kernel(
    const float* __restrict__ nf,    // [N,64] f32
    const float* __restrict__ b1,    // [128]
    const float* __restrict__ W2,    // [128]
    const float* __restrict__ b2,    // [1]
    const int*   __restrict__ src,   // [E]
    const int*   __restrict__ dst,   // [E]
    const __bf16* __restrict__ W1t,  // [128 cols][128 k] bf16
    float* __restrict__ out,         // [N,K]
    int T, int K, int DEG)
{
    const int lane = threadIdx.x & 63;
    const int wid  = threadIdx.x >> 6;
    const int row  = lane & 15;   // edge-in-tile (A row) / col-in-tile (B col)
    const int kg   = lane >> 4;   // k-group 0..3

    // ---- stage all of W1 into registers (once per thread) ----
    bf16x8 bfrag[8][4];
    #pragma unroll
    for (int ct = 0; ct < 8; ++ct) {
        const __bf16* colp = W1t + (ct * 16 + row) * 128 + kg * 8;
        #pragma unroll
        for (int kk = 0; kk < 4; ++kk)
            bfrag[ct][kk] = *(const bf16x8*)(colp + kk * 32);
    }
    float b1c[8], w2c[8];
    #pragma unroll
    for (int ct = 0; ct < 8; ++ct) {
        b1c[ct] = b1[ct * 16 + row];
        w2c[ct] = W2[ct * 16 + row];
    }
    const float b2v = b2[0];

    const int wstride = gridDim.x * 4;
    for (int t = blockIdx.x * 4 + wid; t < T; t += wstride) {
        const long eb = (long)t * DEG;
        const int dv = dst[eb];           // dst node, uniform across tile
        const int sv = src[eb + row];     // this row's src node

        // ---- build A fragments (convert f32 -> bf16) ----
        bf16x8 afrag[4];
        const float* dp = nf + (long)dv * 64 + kg * 8;
        const float* sp = nf + (long)sv * 64 + kg * 8;
        #pragma unroll
        for (int kk = 0; kk < 2; ++kk) {
            f32x4 lo = *(const f32x4*)(dp + kk * 32);
            f32x4 hi = *(const f32x4*)(dp + kk * 32 + 4);
            bf16x8 a;
            #pragma unroll
            for (int j = 0; j < 4; ++j) { a[j] = (__bf16)lo[j]; a[4 + j] = (__bf16)hi[j]; }
            afrag[kk] = a;
        }
        #pragma unroll
        for (int kk = 0; kk < 2; ++kk) {
            f32x4 lo = *(const f32x4*)(sp + kk * 32);
            f32x4 hi = *(const f32x4*)(sp + kk * 32 + 4);
            bf16x8 a;
            #pragma unroll
            for (int j = 0; j < 4; ++j) { a[j] = (__bf16)lo[j]; a[4 + j] = (__bf16)hi[j]; }
            afrag[2 + kk] = a;
        }

        // ---- 32 MFMAs: acc[ct] over 4 K-steps ----
        f32x4 acc[8];
        #pragma unroll
        for (int ct = 0; ct < 8; ++ct) acc[ct] = (f32x4){0.f, 0.f, 0.f, 0.f};
        #pragma unroll
        for (int ct = 0; ct < 8; ++ct) {
            #pragma unroll
            for (int kk = 0; kk < 4; ++kk)
                acc[ct] = __builtin_amdgcn_mfma_f32_16x16x32_bf16(
                    afrag[kk], bfrag[ct][kk], acc[ct], 0, 0, 0);
        }

        // ---- epilogue: leaky_relu + dot(W2) + cross-lane reduce ----
        // lane holds H rows (4*kg + r), col (ct*16 + row)
        float part[4] = {0.f, 0.f, 0.f, 0.f};
        #pragma unroll
        for (int ct = 0; ct < 8; ++ct) {
            #pragma unroll
            for (int r = 0; r < 4; ++r) {
                float h = acc[ct][r] + b1c[ct];
                h = fmaxf(h, 0.01f * h);      // leaky_relu, slope 0.01
                part[r] = fmaf(h, w2c[ct], part[r]);
            }
        }
        // reduce across the 16 lanes (same kg) holding different cols
        #pragma unroll
        for (int m = 1; m < 16; m <<= 1) {
            #pragma unroll
            for (int r = 0; r < 4; ++r)
                part[r] += __shfl_xor(part[r], m, 64);
        }

        float* orow = out + (long)dv * K;
        if (row == 0) {
            f32x4 v;
            #pragma unroll
            for (int r = 0; r < 4; ++r) v[r] = part[r] + b2v;
            *(f32x4*)(orow + kg * 4) = v;     // slots 4*kg .. 4*kg+3
        }
        // filler slots DEG..K-1
        for (int f = lane; f < K - DEG; f += 64)
            orow[DEG + f] = -1e10f;
    }
}

extern "C" void kernel_launch(void* const* d_in, const int* in_sizes, int n_in,
                              void* d_out, int out_size, void* d_ws, size_t ws_size,
                              hipStream_t stream) {
    const float* nf  = (const float*)d_in[0];
    const float* W1  = (const float*)d_in[1];
    const float* b1  = (const float*)d_in[2];
    const float* W2  = (const float*)d_in[3];
    const float* b2  = (const float*)d_in[4];
    const int*   src = (const int*)d_in[5];
    const int*   dst = (const int*)d_in[6];
    float* out = (float*)d_out;

    const int H    = in_sizes[2];          // 128
    const int twoD = in_sizes[1] / H;      // 128
    const int D    = twoD / 2;             // 64
    const int N    = in_sizes[0] / D;      // 100000
    const int E    = in_sizes[5];          // 1600000
    const int DEG  = E / N;                // 16
    const int K    = out_size / N;         // 32
    const int T    = N;                    // one tile per node

    __bf16* W1t = (__bf16*)d_ws;           // 32 KiB
    prep_w1_kernel<<<64, 256, 0, stream>>>(W1, W1t);

    attack_kernel<<<512, 256, 0, stream>>>(nf, b1, W2, b2, src, dst, W1t,
                                           out, T, K, DEG);
}